// Round 5
// baseline (424.796 us; speedup 1.0000x reference)
//
#include <hip/hip_runtime.h>

// UpdateFunction: GRU-ish gated node update, B=64, N=1024, D=256.
//   z = sigmoid(m@w_z + h@u_z); r = sigmoid(m@w_r + h@u_r)
//   htil = tanh(m@w + (r*h)@u); out = mask * ((1-z)*h + z*htil)
// bf16 MFMA 16x16x32, fragment-major pre-packed weights (1KB coalesced B-loads).
// R6: ROWS 32->64 halved weight re-fetch: 239->166us (weight traffic matters).
// R7: chunked dbuf staging + 16 waves + conflict-free swizzle: conflicts
//     6.3M->0, occupancy 22->43%, dur UNCHANGED 167us. Conclusion: stalls are
//     convoy/lockstep - all 16 waves run identical code between barriers,
//     issue loads simultaneously (L2 serializes burst while MFMA idles), MFMA
//     together, stall together. TLP can't hide latency in lockstep.
// R8: per-wave K-rotation rot=(wave*5)&7 - each wave walks its 8-kk chunk at
//     a different phase (K-sum commutes), desynchronizing SIMD-mates so one
//     wave's MFMA covers another's L2/LDS latency. asm keep-alives pin the
//     staged regs so the compiler can't sink the chunk loads to use-point.

#define KTOT 768
#define ROWS 64
#define THREADS 1024
#define CHUNK 256                       // K cols per chunk
#define CHUNK_SHORTS (ROWS * CHUNK)     // 16384 shorts = 32 KB
#define TILE_SHORTS 12288               // 16-col fragment tile: 24kk*64lanes*8bf16

typedef __attribute__((ext_vector_type(8))) __bf16 bf16x8;
typedef __attribute__((ext_vector_type(8))) unsigned short ushort8;
typedef __attribute__((ext_vector_type(4))) float f32x4;

#define MFMA(a, b, c) __builtin_amdgcn_mfma_f32_16x16x32_bf16((a), (b), (c), 0, 0, 0)

__device__ __forceinline__ unsigned short f2bf(float f) {
    union { float f; unsigned u; } v; v.f = f;
    return (unsigned short)((v.u + 0x7FFFu + ((v.u >> 16) & 1u)) >> 16);  // RNE
}
__device__ __forceinline__ float bf2f(unsigned short b) {
    union { unsigned u; float f; } v; v.u = ((unsigned)b) << 16;
    return v.f;
}

// ---------------------------------------------------------------------------
// Pack weights -> bf16, fragment-major.
// For tile t (16 output cols), kk in [0,24), lane in [0,64):
//   chunk addr = ((t*24 + kk)*64 + lane)*8 shorts; p=lane&15, q=lane>>4:
//   element j = W[k = kk*32 + q*8 + j][n = t*16 + p].
// ---------------------------------------------------------------------------
__global__ void pack_weights(const float* __restrict__ wz, const float* __restrict__ uz,
                             const float* __restrict__ wr, const float* __restrict__ ur,
                             const float* __restrict__ w,  const float* __restrict__ u,
                             unsigned short* __restrict__ W1t, unsigned short* __restrict__ W2t)
{
    __shared__ unsigned short buf[KTOT * 16];   // [k][nl], 24 KB
    const int tid = threadIdx.x;
    const int b   = blockIdx.x;

    const float* Wsrc; const float* Usrc; int ncb; unsigned short* outp;
    if (b < 16)      { Wsrc = wz; Usrc = uz; ncb = b * 16;        outp = W1t + b * TILE_SHORTS; }
    else if (b < 32) { Wsrc = wr; Usrc = ur; ncb = (b - 16) * 16; outp = W1t + b * TILE_SHORTS; }
    else             { Wsrc = w;  Usrc = u;  ncb = (b - 32) * 16; outp = W2t + (b - 32) * TILE_SHORTS; }

    #pragma unroll
    for (int i = 0; i < 48; ++i) {
        int id = tid + i * 256;            // 768*16 elements
        int k = id >> 4, nl = id & 15;
        float v = (k < 512) ? Wsrc[k * 256 + ncb + nl]
                            : Usrc[(k - 512) * 256 + ncb + nl];
        buf[id] = f2bf(v);
    }
    __syncthreads();

    #pragma unroll
    for (int i = 0; i < 6; ++i) {
        int c = tid + i * 256;
        int kk = c >> 6, lane = c & 63;
        int p = lane & 15, q = lane >> 4;
        ushort8 pk;
        #pragma unroll
        for (int j = 0; j < 8; ++j)
            pk[j] = buf[(kk * 32 + q * 8 + j) * 16 + p];
        *(ushort8*)(outp + (unsigned)c * 8) = pk;
    }
}

// XOR-swizzled chunk index: 16B blocks permuted in groups of 16 by row&15.
// A-frag ds_read_b128 (16 rows, same k) -> 16 distinct 16B slots = 32 banks,
// conflict-free. Staging b64 writes (consecutive kblk, fixed row) also clean.
__device__ __forceinline__ int cidx(int row, int k) {   // k in [0, CHUNK)
    int kblk = k >> 3;
    int kb2 = (kblk & 16) | ((kblk ^ row) & 15);
    return row * CHUNK + kb2 * 8 + (k & 7);
}

__global__ __launch_bounds__(THREADS, 4) void fused_gru(
    const float* __restrict__ h_in,   // [BN,256]
    const float* __restrict__ msg,    // [BN,512]
    const float* __restrict__ mask,   // [BN]
    const unsigned short* __restrict__ W1t,  // 32 fragment tiles (z|r)
    const unsigned short* __restrict__ W2t,  // 16 fragment tiles
    float* __restrict__ out)          // [BN,256]
{
    __shared__ __align__(16) unsigned short B0[CHUNK_SHORTS];  // 32 KB
    __shared__ __align__(16) unsigned short B1[CHUNK_SHORTS];  // 32 KB
    __shared__ float maskS[ROWS];

    const int tid  = threadIdx.x;
    const int wave = tid >> 6;        // 0..15 -> col tile (cols wave*16..+16)
    const int lane = tid & 63;
    const int p    = lane & 15;
    const int q    = lane >> 4;
    const int rot  = (wave * 5) & 7;  // per-wave K-phase (anti-convoy)
    const long r0  = (long)blockIdx.x * ROWS;

    // ---- staging helpers: issue (global->regs) / write (regs->LDS bf16) ----
    f32x4 st[4];
    auto stage_issue = [&](const float* base, int stride) {
        #pragma unroll
        for (int i = 0; i < 4; ++i) {
            int f = tid + i * THREADS;
            st[i] = *(const f32x4*)(base + (f >> 6) * stride + (f & 63) * 4);
        }
        // pin the loads here - don't let the allocator sink them to use-point
        #pragma unroll
        for (int i = 0; i < 4; ++i) asm volatile("" : "+v"(st[i]));
    };
    auto stage_write = [&](unsigned short* buf) {
        #pragma unroll
        for (int i = 0; i < 4; ++i) {
            int f = tid + i * THREADS;
            int row = f >> 6, c4 = f & 63;
            f32x4 v = st[i];
            unsigned long long pk =  (unsigned long long)f2bf(v.x)
                                  | ((unsigned long long)f2bf(v.y) << 16)
                                  | ((unsigned long long)f2bf(v.z) << 32)
                                  | ((unsigned long long)f2bf(v.w) << 48);
            *(unsigned long long*)&buf[cidx(row, c4 * 4)] = pk;
        }
    };

    // ---- prestage chunk c0 = m[:,0:256] ----
    stage_issue(msg + r0 * 512, 512);
    if (tid < ROWS) maskS[tid] = mask[r0 + tid];
    stage_write(B0);
    __syncthreads();

    // Wave owns fragment tile `wave` of each gate.
    const unsigned short* wzp = W1t + (long)wave * TILE_SHORTS + lane * 8;
    const unsigned short* wrp = wzp + 16L * TILE_SHORTS;
    const unsigned short* wbp = W2t + (long)wave * TILE_SHORTS + lane * 8;

    // ---- Z+R: 3 chunk-steps x 8 kk, each wave phase-rotated within chunk ----
    f32x4 accz[4], accr[4];
    #pragma unroll
    for (int rt = 0; rt < 4; ++rt)
        #pragma unroll
        for (int i = 0; i < 4; ++i) { accz[rt][i] = 0.f; accr[rt][i] = 0.f; }

    bf16x8 zb = *(const bf16x8*)(wzp + rot * 512);
    bf16x8 rb = *(const bf16x8*)(wrp + rot * 512);

    // kk0: global kk base of this chunk; nk0: base of next chunk (-1 = none).
    auto zr_step = [&](const unsigned short* buf, int kk0, int nk0) {
        #pragma unroll
        for (int kkl = 0; kkl < 8; ++kkl) {
            int curl = (kkl + rot) & 7;            // rotated col-index in chunk
            bf16x8 a[4];
            #pragma unroll
            for (int rt = 0; rt < 4; ++rt)
                a[rt] = *(const bf16x8*)&buf[cidx(rt * 16 + p, curl * 32 + q * 8)];
            int nk = (kkl < 7) ? kk0 + ((kkl + 1 + rot) & 7)
                               : (nk0 >= 0 ? nk0 + rot : -1);
            bf16x8 nzb, nrb;
            if (nk >= 0) {
                nzb = *(const bf16x8*)(wzp + nk * 512);
                nrb = *(const bf16x8*)(wrp + nk * 512);
            }
            __builtin_amdgcn_s_setprio(1);
            #pragma unroll
            for (int rt = 0; rt < 4; ++rt) accz[rt] = MFMA(a[rt], zb, accz[rt]);
            #pragma unroll
            for (int rt = 0; rt < 4; ++rt) accr[rt] = MFMA(a[rt], rb, accr[rt]);
            __builtin_amdgcn_s_setprio(0);
            if (nk >= 0) { zb = nzb; rb = nrb; }
        }
    };

    stage_issue(msg + r0 * 512 + 256, 512);   // c1 = m[:,256:512]
    zr_step(B0, 0, 8);
    stage_write(B1);
    __syncthreads();

    stage_issue(h_in + r0 * 256, 256);        // c2 = h
    zr_step(B1, 8, 16);
    stage_write(B0);
    __syncthreads();

    stage_issue(msg + r0 * 512, 512);         // pass-B m0 (re-read, L3-warm)
    zr_step(B0, 16, -1);
    stage_write(B1);
    __syncthreads();

    // ---- sigmoid; cache h; overwrite h -> r*h in place (B0) ----
    float zs[4][4], rs[4][4], hs[4][4];
    #pragma unroll
    for (int rt = 0; rt < 4; ++rt)
        #pragma unroll
        for (int i = 0; i < 4; ++i) {
            zs[rt][i] = 1.f / (1.f + __expf(-accz[rt][i]));
            rs[rt][i] = 1.f / (1.f + __expf(-accr[rt][i]));
        }
    #pragma unroll
    for (int rt = 0; rt < 4; ++rt)
        #pragma unroll
        for (int i = 0; i < 4; ++i) {
            int row = rt * 16 + q * 4 + i;       // C/D: row = quad*4+reg
            int col = wave * 16 + p;             //      col = lane&15
            unsigned short* ptr = &B0[cidx(row, col)];
            float hv = bf2f(*ptr);
            hs[rt][i] = hv;
            *ptr = f2bf(rs[rt][i] * hv);
        }
    __syncthreads();

    // ---- Pass B: htil = tanh([rh | m0 | m1] @ W2t)  (K-order permuted) ----
    f32x4 acc[4];
    #pragma unroll
    for (int rt = 0; rt < 4; ++rt)
        #pragma unroll
        for (int i = 0; i < 4; ++i) acc[rt][i] = 0.f;

    bf16x8 bb = *(const bf16x8*)(wbp + (16 + rot) * 512);  // rh chunk first

    auto b_step = [&](const unsigned short* buf, int kk0, int nk0) {
        #pragma unroll
        for (int kkl = 0; kkl < 8; ++kkl) {
            int curl = (kkl + rot) & 7;
            bf16x8 a[4];
            #pragma unroll
            for (int rt = 0; rt < 4; ++rt)
                a[rt] = *(const bf16x8*)&buf[cidx(rt * 16 + p, curl * 32 + q * 8)];
            int nk = (kkl < 7) ? kk0 + ((kkl + 1 + rot) & 7)
                               : (nk0 >= 0 ? nk0 + rot : -1);
            bf16x8 nbb;
            if (nk >= 0) nbb = *(const bf16x8*)(wbp + nk * 512);
            __builtin_amdgcn_s_setprio(1);
            #pragma unroll
            for (int rt = 0; rt < 4; ++rt) acc[rt] = MFMA(a[rt], bb, acc[rt]);
            __builtin_amdgcn_s_setprio(0);
            if (nk >= 0) bb = nbb;
        }
    };

    stage_issue(msg + r0 * 512 + 256, 512);   // m1 re-read
    b_step(B0, 16, 0);        // rh chunk (weights kk 16..23)
    __syncthreads();          // all waves done reading rh
    stage_write(B0);          // m1 -> B0
    b_step(B1, 0, 8);         // m0 chunk (weights kk 0..7)
    __syncthreads();          // m1 write visible
    b_step(B0, 8, -1);        // m1 chunk (weights kk 8..15)

    // ---- Fused epilogue ----
    #pragma unroll
    for (int rt = 0; rt < 4; ++rt)
        #pragma unroll
        for (int i = 0; i < 4; ++i) {
            int row  = rt * 16 + q * 4 + i;
            long grow = r0 + row;
            int col  = wave * 16 + p;
            float pre = acc[rt][i];
            float e  = __expf(-2.f * fabsf(pre));
            float t  = (1.f - e) / (1.f + e);
            float ht = (pre >= 0.f) ? t : -t;
            float zv = zs[rt][i];
            float hv = hs[rt][i];
            out[grow * 256 + col] = maskS[row] * (hv + zv * (ht - hv));
        }
}

extern "C" void kernel_launch(void* const* d_in, const int* in_sizes, int n_in,
                              void* d_out, int out_size, void* d_ws, size_t ws_size,
                              hipStream_t stream) {
    const float* h_in = (const float*)d_in[0];   // node_state [64,1024,256]
    const float* msg  = (const float*)d_in[1];   // message    [64,1024,512]
    const float* mask = (const float*)d_in[2];   // mask       [64,1024]
    const float* wz   = (const float*)d_in[3];
    const float* uz   = (const float*)d_in[4];
    const float* wr   = (const float*)d_in[5];
    const float* ur   = (const float*)d_in[6];
    const float* w    = (const float*)d_in[7];
    const float* u    = (const float*)d_in[8];

    unsigned short* W1t = (unsigned short*)d_ws;           // 32 tiles
    unsigned short* W2t = W1t + 32 * TILE_SHORTS;          // 16 tiles
    float* out = (float*)d_out;

    pack_weights<<<48, 256, 0, stream>>>(wz, uz, wr, ur, w, u, W1t, W2t);

    const int BN = 64 * 1024;
    fused_gru<<<BN / ROWS, THREADS, 0, stream>>>(h_in, msg, mask, W1t, W2t, out);
}

// Round 6
// 383.995 us; speedup vs baseline: 1.1063x; 1.1063x over previous
//
#include <hip/hip_runtime.h>

// UpdateFunction: GRU-ish gated node update, B=64, N=1024, D=256.
//   z = sigmoid(m@w_z + h@u_z); r = sigmoid(m@w_r + h@u_r)
//   htil = tanh(m@w + (r*h)@u); out = mask * ((1-z)*h + z*htil)
// bf16 MFMA 16x16x32, fragment-major pre-packed weights (1KB coalesced B-loads).
// R6: ROWS 32->64 halved weight re-fetch: 239->166us.
// R7: chunked staging + 16 waves + 0 conflicts: dur UNCHANGED. VGPR=64 proves
//     the staged loads were SUNK to stage_write -> staging stayed serial; and
//     A-frags were same-kk loaded -> ~120cy lgkm wait exposed every kk.
// R8: rotation + asm pin at 64-VGPR budget -> spills (WRITE 65->320MB), 250us.
//     REVERTED rotation. Lesson: pin needs a real register budget.
// R9: (a) amdgpu_waves_per_eu(4,4) -> 128-VGPR budget, pin without spill:
//     chunk loads genuinely in flight across the 8-kk MFMA phase.
//     (b) depth-1 A-frag prefetch within chunk (7/8 kk covered).
//     (c) no rotation, R7 ordering restored.

#define KTOT 768
#define ROWS 64
#define THREADS 1024
#define CHUNK 256                       // K cols per chunk
#define CHUNK_SHORTS (ROWS * CHUNK)     // 16384 shorts = 32 KB
#define TILE_SHORTS 12288               // 16-col fragment tile: 24kk*64lanes*8bf16

typedef __attribute__((ext_vector_type(8))) __bf16 bf16x8;
typedef __attribute__((ext_vector_type(8))) unsigned short ushort8;
typedef __attribute__((ext_vector_type(4))) float f32x4;

#define MFMA(a, b, c) __builtin_amdgcn_mfma_f32_16x16x32_bf16((a), (b), (c), 0, 0, 0)

__device__ __forceinline__ unsigned short f2bf(float f) {
    union { float f; unsigned u; } v; v.f = f;
    return (unsigned short)((v.u + 0x7FFFu + ((v.u >> 16) & 1u)) >> 16);  // RNE
}
__device__ __forceinline__ float bf2f(unsigned short b) {
    union { unsigned u; float f; } v; v.u = ((unsigned)b) << 16;
    return v.f;
}

// ---------------------------------------------------------------------------
// Pack weights -> bf16, fragment-major.
// For tile t (16 output cols), kk in [0,24), lane in [0,64):
//   chunk addr = ((t*24 + kk)*64 + lane)*8 shorts; p=lane&15, q=lane>>4:
//   element j = W[k = kk*32 + q*8 + j][n = t*16 + p].
// ---------------------------------------------------------------------------
__global__ void pack_weights(const float* __restrict__ wz, const float* __restrict__ uz,
                             const float* __restrict__ wr, const float* __restrict__ ur,
                             const float* __restrict__ w,  const float* __restrict__ u,
                             unsigned short* __restrict__ W1t, unsigned short* __restrict__ W2t)
{
    __shared__ unsigned short buf[KTOT * 16];   // [k][nl], 24 KB
    const int tid = threadIdx.x;
    const int b   = blockIdx.x;

    const float* Wsrc; const float* Usrc; int ncb; unsigned short* outp;
    if (b < 16)      { Wsrc = wz; Usrc = uz; ncb = b * 16;        outp = W1t + b * TILE_SHORTS; }
    else if (b < 32) { Wsrc = wr; Usrc = ur; ncb = (b - 16) * 16; outp = W1t + b * TILE_SHORTS; }
    else             { Wsrc = w;  Usrc = u;  ncb = (b - 32) * 16; outp = W2t + (b - 32) * TILE_SHORTS; }

    #pragma unroll
    for (int i = 0; i < 48; ++i) {
        int id = tid + i * 256;            // 768*16 elements
        int k = id >> 4, nl = id & 15;
        float v = (k < 512) ? Wsrc[k * 256 + ncb + nl]
                            : Usrc[(k - 512) * 256 + ncb + nl];
        buf[id] = f2bf(v);
    }
    __syncthreads();

    #pragma unroll
    for (int i = 0; i < 6; ++i) {
        int c = tid + i * 256;
        int kk = c >> 6, lane = c & 63;
        int p = lane & 15, q = lane >> 4;
        ushort8 pk;
        #pragma unroll
        for (int j = 0; j < 8; ++j)
            pk[j] = buf[(kk * 32 + q * 8 + j) * 16 + p];
        *(ushort8*)(outp + (unsigned)c * 8) = pk;
    }
}

// XOR-swizzled chunk index: 16B blocks permuted in groups of 16 by row&15.
// A-frag ds_read_b128 (16 rows, same k) -> conflict-free; staging b64 clean.
__device__ __forceinline__ int cidx(int row, int k) {   // k in [0, CHUNK)
    int kblk = k >> 3;
    int kb2 = (kblk & 16) | ((kblk ^ row) & 15);
    return row * CHUNK + kb2 * 8 + (k & 7);
}

__global__ __launch_bounds__(THREADS)
__attribute__((amdgpu_waves_per_eu(4, 4)))
void fused_gru(
    const float* __restrict__ h_in,   // [BN,256]
    const float* __restrict__ msg,    // [BN,512]
    const float* __restrict__ mask,   // [BN]
    const unsigned short* __restrict__ W1t,  // 32 fragment tiles (z|r)
    const unsigned short* __restrict__ W2t,  // 16 fragment tiles
    float* __restrict__ out)          // [BN,256]
{
    __shared__ __align__(16) unsigned short B0[CHUNK_SHORTS];  // 32 KB
    __shared__ __align__(16) unsigned short B1[CHUNK_SHORTS];  // 32 KB
    __shared__ float maskS[ROWS];

    const int tid  = threadIdx.x;
    const int wave = tid >> 6;        // 0..15 -> col tile (cols wave*16..+16)
    const int lane = tid & 63;
    const int p    = lane & 15;
    const int q    = lane >> 4;
    const long r0  = (long)blockIdx.x * ROWS;

    // ---- staging helpers: issue (global->regs, pinned) / write (->LDS bf16) ----
    f32x4 st[4];
    auto stage_issue = [&](const float* base, int stride) {
        #pragma unroll
        for (int i = 0; i < 4; ++i) {
            int f = tid + i * THREADS;
            st[i] = *(const f32x4*)(base + (f >> 6) * stride + (f & 63) * 4);
        }
        // pin: loads must issue HERE, stay in flight across the MFMA phase
        #pragma unroll
        for (int i = 0; i < 4; ++i) asm volatile("" : "+v"(st[i]));
    };
    auto stage_write = [&](unsigned short* buf) {
        #pragma unroll
        for (int i = 0; i < 4; ++i) {
            int f = tid + i * THREADS;
            int row = f >> 6, c4 = f & 63;
            f32x4 v = st[i];
            unsigned long long pk =  (unsigned long long)f2bf(v.x)
                                  | ((unsigned long long)f2bf(v.y) << 16)
                                  | ((unsigned long long)f2bf(v.z) << 32)
                                  | ((unsigned long long)f2bf(v.w) << 48);
            *(unsigned long long*)&buf[cidx(row, c4 * 4)] = pk;
        }
    };

    // ---- prestage chunk c0 = m[:,0:256] ----
    stage_issue(msg + r0 * 512, 512);
    if (tid < ROWS) maskS[tid] = mask[r0 + tid];
    stage_write(B0);
    __syncthreads();

    // Wave owns fragment tile `wave` of each gate.
    const unsigned short* wzp = W1t + (long)wave * TILE_SHORTS + lane * 8;
    const unsigned short* wrp = wzp + 16L * TILE_SHORTS;
    const unsigned short* wbp = W2t + (long)wave * TILE_SHORTS + lane * 8;

    // ---- Z+R: 3 chunk-steps x 8 kk; A-frags + weights depth-1 prefetched ----
    f32x4 accz[4], accr[4];
    #pragma unroll
    for (int rt = 0; rt < 4; ++rt)
        #pragma unroll
        for (int i = 0; i < 4; ++i) { accz[rt][i] = 0.f; accr[rt][i] = 0.f; }

    bf16x8 zb = *(const bf16x8*)(wzp);
    bf16x8 rb = *(const bf16x8*)(wrp);

    // kk0: global kk base of this chunk (weights); nk0 >= 0: prefetch next chunk's
    // first weight frag on the last iteration.
    auto zr_step = [&](const unsigned short* buf, int kk0, int nk0) {
        bf16x8 a[4];
        #pragma unroll
        for (int rt = 0; rt < 4; ++rt)
            a[rt] = *(const bf16x8*)&buf[cidx(rt * 16 + p, q * 8)];
        #pragma unroll
        for (int kkl = 0; kkl < 8; ++kkl) {
            int kkg = kk0 + kkl;
            bf16x8 na[4], nzb, nrb;
            if (kkl < 7) {
                #pragma unroll
                for (int rt = 0; rt < 4; ++rt)
                    na[rt] = *(const bf16x8*)&buf[cidx(rt * 16 + p, (kkl + 1) * 32 + q * 8)];
            }
            int nk = (kkl < 7) ? (kkg + 1) : nk0;
            if (nk >= 0) {
                nzb = *(const bf16x8*)(wzp + nk * 512);
                nrb = *(const bf16x8*)(wrp + nk * 512);
            }
            __builtin_amdgcn_s_setprio(1);
            #pragma unroll
            for (int rt = 0; rt < 4; ++rt) accz[rt] = MFMA(a[rt], zb, accz[rt]);
            #pragma unroll
            for (int rt = 0; rt < 4; ++rt) accr[rt] = MFMA(a[rt], rb, accr[rt]);
            __builtin_amdgcn_s_setprio(0);
            if (kkl < 7) {
                #pragma unroll
                for (int rt = 0; rt < 4; ++rt) a[rt] = na[rt];
            }
            if (nk >= 0) { zb = nzb; rb = nrb; }
        }
    };

    stage_issue(msg + r0 * 512 + 256, 512);   // c1 = m[:,256:512]
    zr_step(B0, 0, 8);
    stage_write(B1);
    __syncthreads();

    stage_issue(h_in + r0 * 256, 256);        // c2 = h
    zr_step(B1, 8, 16);
    stage_write(B0);
    __syncthreads();

    stage_issue(msg + r0 * 512, 512);         // pass-B m0 (re-read, L3-warm)
    zr_step(B0, 16, -1);
    stage_write(B1);
    __syncthreads();

    // ---- sigmoid; cache h; overwrite h -> r*h in place (B0) ----
    float zs[4][4], rs[4][4], hs[4][4];
    #pragma unroll
    for (int rt = 0; rt < 4; ++rt)
        #pragma unroll
        for (int i = 0; i < 4; ++i) {
            zs[rt][i] = 1.f / (1.f + __expf(-accz[rt][i]));
            rs[rt][i] = 1.f / (1.f + __expf(-accr[rt][i]));
        }
    #pragma unroll
    for (int rt = 0; rt < 4; ++rt)
        #pragma unroll
        for (int i = 0; i < 4; ++i) {
            int row = rt * 16 + q * 4 + i;       // C/D: row = quad*4+reg
            int col = wave * 16 + p;             //      col = lane&15
            unsigned short* ptr = &B0[cidx(row, col)];
            float hv = bf2f(*ptr);
            hs[rt][i] = hv;
            *ptr = f2bf(rs[rt][i] * hv);
        }
    __syncthreads();

    // ---- Pass B: htil = tanh([rh | m0 | m1] @ W2t)  (K-order permuted) ----
    f32x4 acc[4];
    #pragma unroll
    for (int rt = 0; rt < 4; ++rt)
        #pragma unroll
        for (int i = 0; i < 4; ++i) acc[rt][i] = 0.f;

    bf16x8 bb = *(const bf16x8*)(wbp + 16 * 512);   // rh chunk = physical kk 16..23

    auto b_step = [&](const unsigned short* buf, int kk0, int nk0) {
        bf16x8 a[4];
        #pragma unroll
        for (int rt = 0; rt < 4; ++rt)
            a[rt] = *(const bf16x8*)&buf[cidx(rt * 16 + p, q * 8)];
        #pragma unroll
        for (int kkl = 0; kkl < 8; ++kkl) {
            int kkg = kk0 + kkl;
            bf16x8 na[4], nbb;
            if (kkl < 7) {
                #pragma unroll
                for (int rt = 0; rt < 4; ++rt)
                    na[rt] = *(const bf16x8*)&buf[cidx(rt * 16 + p, (kkl + 1) * 32 + q * 8)];
            }
            int nk = (kkl < 7) ? (kkg + 1) : nk0;
            if (nk >= 0) nbb = *(const bf16x8*)(wbp + nk * 512);
            __builtin_amdgcn_s_setprio(1);
            #pragma unroll
            for (int rt = 0; rt < 4; ++rt) acc[rt] = MFMA(a[rt], bb, acc[rt]);
            __builtin_amdgcn_s_setprio(0);
            if (kkl < 7) {
                #pragma unroll
                for (int rt = 0; rt < 4; ++rt) a[rt] = na[rt];
            }
            if (nk >= 0) bb = nbb;
        }
    };

    stage_issue(msg + r0 * 512 + 256, 512);   // m1 re-read
    b_step(B0, 16, 0);        // rh chunk (weights kk 16..23)
    __syncthreads();          // all waves done reading rh
    stage_write(B0);          // m1 -> B0
    b_step(B1, 0, 8);         // m0 chunk (weights kk 0..7)
    __syncthreads();          // m1 write visible
    b_step(B0, 8, -1);        // m1 chunk (weights kk 8..15)

    // ---- Fused epilogue ----
    #pragma unroll
    for (int rt = 0; rt < 4; ++rt)
        #pragma unroll
        for (int i = 0; i < 4; ++i) {
            int row  = rt * 16 + q * 4 + i;
            long grow = r0 + row;
            int col  = wave * 16 + p;
            float pre = acc[rt][i];
            float e  = __expf(-2.f * fabsf(pre));
            float t  = (1.f - e) / (1.f + e);
            float ht = (pre >= 0.f) ? t : -t;
            float zv = zs[rt][i];
            float hv = hs[rt][i];
            out[grow * 256 + col] = maskS[row] * (hv + zv * (ht - hv));
        }
}

extern "C" void kernel_launch(void* const* d_in, const int* in_sizes, int n_in,
                              void* d_out, int out_size, void* d_ws, size_t ws_size,
                              hipStream_t stream) {
    const float* h_in = (const float*)d_in[0];   // node_state [64,1024,256]
    const float* msg  = (const float*)d_in[1];   // message    [64,1024,512]
    const float* mask = (const float*)d_in[2];   // mask       [64,1024]
    const float* wz   = (const float*)d_in[3];
    const float* uz   = (const float*)d_in[4];
    const float* wr   = (const float*)d_in[5];
    const float* ur   = (const float*)d_in[6];
    const float* w    = (const float*)d_in[7];
    const float* u    = (const float*)d_in[8];

    unsigned short* W1t = (unsigned short*)d_ws;           // 32 tiles
    unsigned short* W2t = W1t + 32 * TILE_SHORTS;          // 16 tiles
    float* out = (float*)d_out;

    pack_weights<<<48, 256, 0, stream>>>(wz, uz, wr, ur, w, u, W1t, W2t);

    const int BN = 64 * 1024;
    fused_gru<<<BN / ROWS, THREADS, 0, stream>>>(h_in, msg, mask, W1t, W2t, out);
}

// Round 7
// 370.725 us; speedup vs baseline: 1.1459x; 1.0358x over previous
//
#include <hip/hip_runtime.h>

// UpdateFunction: GRU-ish gated node update, B=64, N=1024, D=256.
//   z = sigmoid(m@w_z + h@u_z); r = sigmoid(m@w_r + h@u_r)
//   htil = tanh(m@w + (r*h)@u); out = mask * ((1-z)*h + z*htil)
// bf16 MFMA 16x16x32, fragment-major pre-packed weights (1KB coalesced B-loads).
// R6: ROWS 32->64 halved weight re-fetch: 239->166us.
// R7: chunked staging + 16 waves + 0 conflicts: dur UNCHANGED 167us.
// R8/R9: pin/rotation at 64-VGPR budget -> scratch spills (WRITE 175-320MB).
//   ROOT CAUSE FOUND: __launch_bounds__(1024) alone => compiler targets
//   8 waves/EU => hard 64-VGPR cap => every prefetch was either serialized
//   (R7, loads sunk to use) or spilled (R8/R9). R6 proves the lever:
//   launch_bounds(512,2) gave VGPR=108.
// R10: (a) __launch_bounds__(1024,4) => 128-VGPR budget, 1 block/CU.
//      (b) weight frags depth-2 prefetch (2-slot ring, static kkl&1 index)
//          -> ~2 kk-steps (~260+ cyc) cover for L2 latency.
//      (c) A-frags depth-1 (LDS ~120cy, 1 kk covers). Staging pin kept.

#define KTOT 768
#define ROWS 64
#define THREADS 1024
#define CHUNK 256                       // K cols per chunk
#define CHUNK_SHORTS (ROWS * CHUNK)     // 16384 shorts = 32 KB
#define TILE_SHORTS 12288               // 16-col fragment tile: 24kk*64lanes*8bf16

typedef __attribute__((ext_vector_type(8))) __bf16 bf16x8;
typedef __attribute__((ext_vector_type(8))) unsigned short ushort8;
typedef __attribute__((ext_vector_type(4))) float f32x4;

#define MFMA(a, b, c) __builtin_amdgcn_mfma_f32_16x16x32_bf16((a), (b), (c), 0, 0, 0)

__device__ __forceinline__ unsigned short f2bf(float f) {
    union { float f; unsigned u; } v; v.f = f;
    return (unsigned short)((v.u + 0x7FFFu + ((v.u >> 16) & 1u)) >> 16);  // RNE
}
__device__ __forceinline__ float bf2f(unsigned short b) {
    union { unsigned u; float f; } v; v.u = ((unsigned)b) << 16;
    return v.f;
}

// ---------------------------------------------------------------------------
// Pack weights -> bf16, fragment-major.
// For tile t (16 output cols), kk in [0,24), lane in [0,64):
//   chunk addr = ((t*24 + kk)*64 + lane)*8 shorts; p=lane&15, q=lane>>4:
//   element j = W[k = kk*32 + q*8 + j][n = t*16 + p].
// ---------------------------------------------------------------------------
__global__ void pack_weights(const float* __restrict__ wz, const float* __restrict__ uz,
                             const float* __restrict__ wr, const float* __restrict__ ur,
                             const float* __restrict__ w,  const float* __restrict__ u,
                             unsigned short* __restrict__ W1t, unsigned short* __restrict__ W2t)
{
    __shared__ unsigned short buf[KTOT * 16];   // [k][nl], 24 KB
    const int tid = threadIdx.x;
    const int b   = blockIdx.x;

    const float* Wsrc; const float* Usrc; int ncb; unsigned short* outp;
    if (b < 16)      { Wsrc = wz; Usrc = uz; ncb = b * 16;        outp = W1t + b * TILE_SHORTS; }
    else if (b < 32) { Wsrc = wr; Usrc = ur; ncb = (b - 16) * 16; outp = W1t + b * TILE_SHORTS; }
    else             { Wsrc = w;  Usrc = u;  ncb = (b - 32) * 16; outp = W2t + (b - 32) * TILE_SHORTS; }

    #pragma unroll
    for (int i = 0; i < 48; ++i) {
        int id = tid + i * 256;            // 768*16 elements
        int k = id >> 4, nl = id & 15;
        float v = (k < 512) ? Wsrc[k * 256 + ncb + nl]
                            : Usrc[(k - 512) * 256 + ncb + nl];
        buf[id] = f2bf(v);
    }
    __syncthreads();

    #pragma unroll
    for (int i = 0; i < 6; ++i) {
        int c = tid + i * 256;
        int kk = c >> 6, lane = c & 63;
        int p = lane & 15, q = lane >> 4;
        ushort8 pk;
        #pragma unroll
        for (int j = 0; j < 8; ++j)
            pk[j] = buf[(kk * 32 + q * 8 + j) * 16 + p];
        *(ushort8*)(outp + (unsigned)c * 8) = pk;
    }
}

// XOR-swizzled chunk index: 16B blocks permuted in groups of 16 by row&15.
// A-frag ds_read_b128 (16 rows, same k) -> conflict-free; staging b64 clean.
__device__ __forceinline__ int cidx(int row, int k) {   // k in [0, CHUNK)
    int kblk = k >> 3;
    int kb2 = (kblk & 16) | ((kblk ^ row) & 15);
    return row * CHUNK + kb2 * 8 + (k & 7);
}

__global__ __launch_bounds__(THREADS, 4)   // 4 waves/EU floor -> 128-VGPR cap
void fused_gru(
    const float* __restrict__ h_in,   // [BN,256]
    const float* __restrict__ msg,    // [BN,512]
    const float* __restrict__ mask,   // [BN]
    const unsigned short* __restrict__ W1t,  // 32 fragment tiles (z|r)
    const unsigned short* __restrict__ W2t,  // 16 fragment tiles
    float* __restrict__ out)          // [BN,256]
{
    __shared__ __align__(16) unsigned short B0[CHUNK_SHORTS];  // 32 KB
    __shared__ __align__(16) unsigned short B1[CHUNK_SHORTS];  // 32 KB
    __shared__ float maskS[ROWS];

    const int tid  = threadIdx.x;
    const int wave = tid >> 6;        // 0..15 -> col tile (cols wave*16..+16)
    const int lane = tid & 63;
    const int p    = lane & 15;
    const int q    = lane >> 4;
    const long r0  = (long)blockIdx.x * ROWS;

    // ---- staging helpers: issue (global->regs, pinned) / write (->LDS bf16) ----
    f32x4 st[4];
    auto stage_issue = [&](const float* base, int stride) {
        #pragma unroll
        for (int i = 0; i < 4; ++i) {
            int f = tid + i * THREADS;
            st[i] = *(const f32x4*)(base + (f >> 6) * stride + (f & 63) * 4);
        }
        // pin: loads must issue HERE, stay in flight across the MFMA phase
        #pragma unroll
        for (int i = 0; i < 4; ++i) asm volatile("" : "+v"(st[i]));
    };
    auto stage_write = [&](unsigned short* buf) {
        #pragma unroll
        for (int i = 0; i < 4; ++i) {
            int f = tid + i * THREADS;
            int row = f >> 6, c4 = f & 63;
            f32x4 v = st[i];
            unsigned long long pk =  (unsigned long long)f2bf(v.x)
                                  | ((unsigned long long)f2bf(v.y) << 16)
                                  | ((unsigned long long)f2bf(v.z) << 32)
                                  | ((unsigned long long)f2bf(v.w) << 48);
            *(unsigned long long*)&buf[cidx(row, c4 * 4)] = pk;
        }
    };

    // ---- prestage chunk c0 = m[:,0:256] ----
    stage_issue(msg + r0 * 512, 512);
    if (tid < ROWS) maskS[tid] = mask[r0 + tid];
    stage_write(B0);
    __syncthreads();

    // Wave owns fragment tile `wave` of each gate.
    const unsigned short* wzp = W1t + (long)wave * TILE_SHORTS + lane * 8;
    const unsigned short* wrp = wzp + 16L * TILE_SHORTS;
    const unsigned short* wbp = W2t + (long)wave * TILE_SHORTS + lane * 8;

    // ---- Z+R: 3 chunk-steps x 8 kk ----
    // Weights: depth-2 prefetch via 2-slot ring (slot = kkl&1; kk0 always even
    // so global parity == kkl parity). A-frags: depth-1 within chunk.
    f32x4 accz[4], accr[4];
    #pragma unroll
    for (int rt = 0; rt < 4; ++rt)
        #pragma unroll
        for (int i = 0; i < 4; ++i) { accz[rt][i] = 0.f; accr[rt][i] = 0.f; }

    bf16x8 zq[2], rq[2];
    zq[0] = *(const bf16x8*)(wzp);            // w(0)
    zq[1] = *(const bf16x8*)(wzp + 512);      // w(1)
    rq[0] = *(const bf16x8*)(wrp);
    rq[1] = *(const bf16x8*)(wrp + 512);

    // kk0: global kk base of this chunk (0/8/16); weights linear 0..23.
    auto zr_step = [&](const unsigned short* buf, int kk0) {
        bf16x8 a[4];
        #pragma unroll
        for (int rt = 0; rt < 4; ++rt)
            a[rt] = *(const bf16x8*)&buf[cidx(rt * 16 + p, q * 8)];
        #pragma unroll
        for (int kkl = 0; kkl < 8; ++kkl) {
            const int g = kk0 + kkl;               // global kk of this iter
            bf16x8 na[4];
            if (kkl < 7) {
                #pragma unroll
                for (int rt = 0; rt < 4; ++rt)
                    na[rt] = *(const bf16x8*)&buf[cidx(rt * 16 + p, (kkl + 1) * 32 + q * 8)];
            }
            __builtin_amdgcn_s_setprio(1);
            #pragma unroll
            for (int rt = 0; rt < 4; ++rt) accz[rt] = MFMA(a[rt], zq[kkl & 1], accz[rt]);
            #pragma unroll
            for (int rt = 0; rt < 4; ++rt) accr[rt] = MFMA(a[rt], rq[kkl & 1], accr[rt]);
            __builtin_amdgcn_s_setprio(0);
            // refill the just-consumed slot with w(g+2): 2-kk latency window
            if (g + 2 <= 23) {
                zq[kkl & 1] = *(const bf16x8*)(wzp + (g + 2) * 512);
                rq[kkl & 1] = *(const bf16x8*)(wrp + (g + 2) * 512);
            }
            if (kkl < 7) {
                #pragma unroll
                for (int rt = 0; rt < 4; ++rt) a[rt] = na[rt];
            }
        }
    };

    stage_issue(msg + r0 * 512 + 256, 512);   // c1 = m[:,256:512]
    zr_step(B0, 0);
    stage_write(B1);
    __syncthreads();

    stage_issue(h_in + r0 * 256, 256);        // c2 = h
    zr_step(B1, 8);
    stage_write(B0);
    __syncthreads();

    stage_issue(msg + r0 * 512, 512);         // pass-B m0 (re-read, L3-warm)
    zr_step(B0, 16);
    stage_write(B1);
    __syncthreads();

    // ---- sigmoid; cache h; overwrite h -> r*h in place (B0) ----
    float zs[4][4], rs[4][4], hs[4][4];
    #pragma unroll
    for (int rt = 0; rt < 4; ++rt)
        #pragma unroll
        for (int i = 0; i < 4; ++i) {
            zs[rt][i] = 1.f / (1.f + __expf(-accz[rt][i]));
            rs[rt][i] = 1.f / (1.f + __expf(-accr[rt][i]));
        }
    #pragma unroll
    for (int rt = 0; rt < 4; ++rt)
        #pragma unroll
        for (int i = 0; i < 4; ++i) {
            int row = rt * 16 + q * 4 + i;       // C/D: row = quad*4+reg
            int col = wave * 16 + p;             //      col = lane&15
            unsigned short* ptr = &B0[cidx(row, col)];
            float hv = bf2f(*ptr);
            hs[rt][i] = hv;
            *ptr = f2bf(rs[rt][i] * hv);
        }
    __syncthreads();

    // ---- Pass B: htil = tanh([rh | m0 | m1] @ W2t) ----
    // Weight position order: 16..23, 0..7, 8..15. Ring slot = kkl&1 (bases even).
    f32x4 acc[4];
    #pragma unroll
    for (int rt = 0; rt < 4; ++rt)
        #pragma unroll
        for (int i = 0; i < 4; ++i) acc[rt][i] = 0.f;

    bf16x8 bq[2];
    bq[0] = *(const bf16x8*)(wbp + 16 * 512);  // position 0 -> w(16)
    bq[1] = *(const bf16x8*)(wbp + 17 * 512);  // position 1 -> w(17)

    // kk0: weight base of this chunk; nk0: weight base of NEXT chunk (-1 none).
    auto b_step = [&](const unsigned short* buf, int kk0, int nk0) {
        bf16x8 a[4];
        #pragma unroll
        for (int rt = 0; rt < 4; ++rt)
            a[rt] = *(const bf16x8*)&buf[cidx(rt * 16 + p, q * 8)];
        #pragma unroll
        for (int kkl = 0; kkl < 8; ++kkl) {
            bf16x8 na[4];
            if (kkl < 7) {
                #pragma unroll
                for (int rt = 0; rt < 4; ++rt)
                    na[rt] = *(const bf16x8*)&buf[cidx(rt * 16 + p, (kkl + 1) * 32 + q * 8)];
            }
            __builtin_amdgcn_s_setprio(1);
            #pragma unroll
            for (int rt = 0; rt < 4; ++rt) acc[rt] = MFMA(a[rt], bq[kkl & 1], acc[rt]);
            __builtin_amdgcn_s_setprio(0);
            // position t+2: within chunk -> kk0+kkl+2; crossing -> nk0 / nk0+1
            int nk = (kkl < 6) ? (kk0 + kkl + 2)
                               : (nk0 >= 0 ? nk0 + (kkl - 6) : -1);
            if (nk >= 0)
                bq[kkl & 1] = *(const bf16x8*)(wbp + nk * 512);
            if (kkl < 7) {
                #pragma unroll
                for (int rt = 0; rt < 4; ++rt) a[rt] = na[rt];
            }
        }
    };

    stage_issue(msg + r0 * 512 + 256, 512);   // m1 re-read
    b_step(B0, 16, 0);        // rh chunk (weights 16..23), prefetch -> 0,1
    __syncthreads();          // all waves done reading rh
    stage_write(B0);          // m1 -> B0
    b_step(B1, 0, 8);         // m0 chunk (weights 0..7), prefetch -> 8,9
    __syncthreads();          // m1 write visible
    b_step(B0, 8, -1);        // m1 chunk (weights 8..15)

    // ---- Fused epilogue ----
    #pragma unroll
    for (int rt = 0; rt < 4; ++rt)
        #pragma unroll
        for (int i = 0; i < 4; ++i) {
            int row  = rt * 16 + q * 4 + i;
            long grow = r0 + row;
            int col  = wave * 16 + p;
            float pre = acc[rt][i];
            float e  = __expf(-2.f * fabsf(pre));
            float t  = (1.f - e) / (1.f + e);
            float ht = (pre >= 0.f) ? t : -t;
            float zv = zs[rt][i];
            float hv = hs[rt][i];
            out[grow * 256 + col] = maskS[row] * (hv + zv * (ht - hv));
        }
}

extern "C" void kernel_launch(void* const* d_in, const int* in_sizes, int n_in,
                              void* d_out, int out_size, void* d_ws, size_t ws_size,
                              hipStream_t stream) {
    const float* h_in = (const float*)d_in[0];   // node_state [64,1024,256]
    const float* msg  = (const float*)d_in[1];   // message    [64,1024,512]
    const float* mask = (const float*)d_in[2];   // mask       [64,1024]
    const float* wz   = (const float*)d_in[3];
    const float* uz   = (const float*)d_in[4];
    const float* wr   = (const float*)d_in[5];
    const float* ur   = (const float*)d_in[6];
    const float* w    = (const float*)d_in[7];
    const float* u    = (const float*)d_in[8];

    unsigned short* W1t = (unsigned short*)d_ws;           // 32 tiles
    unsigned short* W2t = W1t + 32 * TILE_SHORTS;          // 16 tiles
    float* out = (float*)d_out;

    pack_weights<<<48, 256, 0, stream>>>(wz, uz, wr, ur, w, u, W1t, W2t);

    const int BN = 64 * 1024;
    fused_gru<<<BN / ROWS, THREADS, 0, stream>>>(h_in, msg, mask, W1t, W2t, out);
}